// Round 9
// baseline (83.413 us; speedup 1.0000x reference)
//
#include <hip/hip_runtime.h>

#define CDIM 256
#define SCALING 0.17677669529663687f  // 32^-0.5

typedef _Float16 f16;
typedef f16 f16x4 __attribute__((ext_vector_type(4)));
typedef f16 f16x8 __attribute__((ext_vector_type(8)));
typedef float f32x4 __attribute__((ext_vector_type(4)));

// Standard gfx950 16x16x32 f16 fragment mapping (m89-verified D; bench-verified A/B):
//   A[m][k]: lane l, reg j  ->  m = l&15,          k = 8*(l>>4) + j   (k contiguous)
//   B[k][n]: lane l, reg j  ->  k = 8*(l>>4) + j,  n = l&15           (k contiguous)
//   D[m][n]: lane l, reg r  ->  m = 4*(l>>4) + r,  n = l&15
#define MFMA(a, b, c) __builtin_amdgcn_mfma_f32_16x16x32_f16(a, b, c, 0, 0, 0)

__device__ __forceinline__ unsigned pack2(float a, float b) {
  union { f16 h[2]; unsigned u; } r;
  r.h[0] = (f16)a;
  r.h[1] = (f16)b;
  return r.u;
}

// ---------------- K0: W2_hd = scaling * wk_hd^T @ wq_hd ; b2 ; wv -> f16 ----------------
// grid (32 ci-octs, 8 hd) x 256 (t = cx)
__global__ __launch_bounds__(256) void k_prep_w2(const float* __restrict__ wq,
                                                 const float* __restrict__ bq,
                                                 const float* __restrict__ wk,
                                                 const float* __restrict__ wv,
                                                 f16* __restrict__ W2h,
                                                 float* __restrict__ b2,
                                                 f16* __restrict__ wvh) {
  __shared__ float wk_s[32][8];
  const int t = threadIdx.x, ciO = blockIdx.x, hd = blockIdx.y;
  {
    int j = t >> 3, c8 = t & 7;
    wk_s[j][c8] = wk[(hd * 32 + j) * CDIM + ciO * 8 + c8];
    int idx = (hd * 32 + j) * CDIM + ciO * 8 + c8;
    wvh[idx] = (f16)wv[idx];
  }
  float wq_r[32];
#pragma unroll
  for (int j = 0; j < 32; ++j) wq_r[j] = wq[(hd * 32 + j) * CDIM + t];
  __syncthreads();
  for (int c8 = 0; c8 < 8; ++c8) {
    float acc = 0.f;
#pragma unroll
    for (int j = 0; j < 32; ++j) acc = fmaf(wq_r[j], wk_s[j][c8], acc);
    W2h[(size_t)(hd * CDIM + ciO * 8 + c8) * CDIM + t] = (f16)(acc * SCALING);
  }
  if (t < 8) {
    float a = 0.f;
    for (int j = 0; j < 32; ++j) a = fmaf(wk_s[j][t], bq[hd * 32 + j], a);
    b2[hd * CDIM + ciO * 8 + t] = a * SCALING;
  }
}

// ---------------- K1: qk[b][pix][hd][ci] = W2_hd @ x + b2 ; gate ----------------
// grid (16 pix-64-slices, 8 hd, nb) x 256. M=256ci, N=64pix, K=256cx.
// A-fragments DIRECT from global W2h (L2-hot); B (x, needs f32->f16 transpose) via
// double-buffered LDS -> 1 barrier per K-step.
__global__ __launch_bounds__(256, 2) void k_qkw2(const float* __restrict__ x,
                                                 const f16* __restrict__ W2h,
                                                 const float* __restrict__ b2,
                                                 const float* __restrict__ wg,
                                                 const float* __restrict__ bg,
                                                 f16* __restrict__ qk,
                                                 float* __restrict__ gw, int b0) {
  __shared__ __align__(16) f16 B_l[2][64 * 40];  // [buf][pix][32cx + 8 pad] 10240 B
  const int t = threadIdx.x;
  const int p16 = blockIdx.x, hd = blockIdx.y, bz = blockIdx.z;
  const int bb = b0 + bz;
  const int lane = t & 63, wid = t >> 6, l15 = lane & 15, h4 = lane >> 4;
  const f16* Whd = W2h + (size_t)hd * CDIM * CDIM;
  f32x4 acc[4][4] = {};
  float gacc = 0.f;

  // stage helper (kb slice of x, transposed to [pix][cx])
  const int s_cx = t >> 4, s_p4 = t & 15;
  const float* xs0 = x + (size_t)(bb * CDIM + s_cx) * 1024 + p16 * 64 + s_p4 * 4;
#define STAGE_B(kb_, buf_)                                              \
  {                                                                     \
    float4 v0 = *(const float4*)(xs0 + (size_t)((kb_)*32) * 1024);      \
    float4 v1 = *(const float4*)(xs0 + (size_t)((kb_)*32 + 16) * 1024); \
    f16* d0 = &B_l[buf_][(s_p4 * 4) * 40 + s_cx];                       \
    d0[0 * 40] = (f16)v0.x; d0[1 * 40] = (f16)v0.y;                     \
    d0[2 * 40] = (f16)v0.z; d0[3 * 40] = (f16)v0.w;                     \
    f16* d1 = d0 + 16;                                                  \
    d1[0 * 40] = (f16)v1.x; d1[1 * 40] = (f16)v1.y;                     \
    d1[2 * 40] = (f16)v1.z; d1[3 * 40] = (f16)v1.w;                     \
  }

  STAGE_B(0, 0);
  for (int kb = 0; kb < 8; ++kb) {
    __syncthreads();  // prev buf reads done (last iter) + this buf writes visible
    if (kb < 7) STAGE_B(kb + 1, (kb + 1) & 1);
    const f16* Bcur = B_l[kb & 1];
    if (hd == 0 && wid == 3) {  // gate partial: pixel = lane
#pragma unroll
      for (int cx = 0; cx < 32; ++cx)
        gacc = fmaf(wg[kb * 32 + cx], (float)Bcur[lane * 40 + cx], gacc);
    }
    f16x8 a[4], bf[4];
#pragma unroll
    for (int mt = 0; mt < 4; ++mt)  // A direct: [m=ci][k=cx], 16B, 64B-contig per h4 group
      a[mt] = *(const f16x8*)(Whd + (size_t)(wid * 64 + mt * 16 + l15) * CDIM + kb * 32 +
                              h4 * 8);
#pragma unroll
    for (int nt = 0; nt < 4; ++nt)
      bf[nt] = *(const f16x8*)(Bcur + (nt * 16 + l15) * 40 + h4 * 8);
#pragma unroll
    for (int mt = 0; mt < 4; ++mt)
#pragma unroll
      for (int nt = 0; nt < 4; ++nt) acc[mt][nt] = MFMA(a[mt], bf[nt], acc[mt][nt]);
  }
#pragma unroll
  for (int mt = 0; mt < 4; ++mt) {
    int ci0 = wid * 64 + mt * 16 + h4 * 4;
    float4 bvv = *(const float4*)(b2 + hd * CDIM + ci0);
#pragma unroll
    for (int nt = 0; nt < 4; ++nt) {
      int pix = p16 * 64 + nt * 16 + l15;
      union { f16 h[4]; unsigned long long u; } P;
      P.h[0] = (f16)(acc[mt][nt][0] + bvv.x);
      P.h[1] = (f16)(acc[mt][nt][1] + bvv.y);
      P.h[2] = (f16)(acc[mt][nt][2] + bvv.z);
      P.h[3] = (f16)(acc[mt][nt][3] + bvv.w);
      *(unsigned long long*)(qk + ((size_t)(bz * 1024 + pix) * 8 + hd) * CDIM + ci0) = P.u;
    }
  }
  if (hd == 0 && wid == 3)
    gw[bz * 1024 + p16 * 64 + lane] = 1.f / (1.f + __expf(-(gacc + bg[0])));
#undef STAGE_B
}

// ---------------- K2: fused local attention (single layout, 1 barrier, 4 blk/CU) ------
// block (h, w4, b): 4 query pixels, wave w owns pixel w. LDS = 40960 B exactly.
// cip[px][256ci][18] (16 p + 2 ZEROED pad; stride-18 -> conflict-free P3/P5 reads)
// P3 : logits[16hd][16p] = qk[16hd][256ci] @ feat[256ci][16p]  (8 MFMA; B via 8 u16 reads)
// P5'': fa[16ci][16hd]   = feat[256ci][32p-junk] @ attn[32p][16hd]  (16 MFMA; attn rows
//       16-31 ZERO kill the junk — junk must be FINITE, hence the pad zeroing)
__global__ __launch_bounds__(256, 4) void k_attn(const float* __restrict__ feat,
                                                 const f16* __restrict__ qk,
                                                 f16* __restrict__ fa, int b0) {
  __shared__ __align__(16) f16 cip[4 * 4608];    // 36864 B [px][ci][18]
  __shared__ __align__(16) f16 attn_l[4 * 512];  //  4096 B [w][32p][16hd]
  const int t = threadIdx.x;
  const int h = blockIdx.x, w4 = blockIdx.y, bz = blockIdx.z;
  const int bb = b0 + bz;
  const int lane = t & 63, w = t >> 6, l15 = lane & 15, h4 = lane >> 4;
  const int pixb = h * 32 + w4 * 4;

  {  // zero attn_l: p>=16 rows = K-padding zeros; hd>=8 cols = zeros (discarded)
    f16x8 z = {};
    *(f16x8*)(attn_l + t * 8) = z;
  }
  // zero every row's 2-f16 pad: P5 A-fragments read them as k=16,17 junk against
  // zero attn rows — junk must be finite (NaN x 0 = NaN), so pads must be 0/finite.
#pragma unroll
  for (int it = 0; it < 4; ++it) {
    int e = it * 256 + t, px = e >> 8, ci = e & 255;
    *(unsigned*)(cip + px * 4608 + ci * 18 + 16) = 0;
  }
  // stage feat patch: thread -> (px, r, ci) float4 (cols px*4..+3 = p r*4..+3 of pixel px)
  const float* fb = feat + (size_t)bb * (CDIM * 16384) + (h * 4) * 128 + w4 * 16;
#pragma unroll
  for (int it = 0; it < 16; ++it) {
    int e = it * 256 + t, px = e & 3, r = (e >> 2) & 3, ci = e >> 4;
    float4 v = *(const float4*)(fb + (size_t)ci * 16384 + r * 128 + px * 4);
    unsigned* d = (unsigned*)(cip + px * 4608 + ci * 18 + r * 4);  // 4B-aligned
    d[0] = pack2(v.x, v.y);
    d[1] = pack2(v.z, v.w);
  }
  __syncthreads();

  // ---- P3: logits[hd][p]; A from global qk (rows 8-15 alias 0-7, dupes discarded) ----
  const f16* qkg = qk + ((size_t)(bz * 1024 + pixb + w) * 8 + (l15 & 7)) * CDIM;
  const f16* cw = cip + w * 4608;
  f32x4 acc = {};
#pragma unroll
  for (int kb = 0; kb < 8; ++kb) {
    f16x8 a = *(const f16x8*)(qkg + kb * 32 + h4 * 8);  // A[hd][ci], k contiguous
    f16x8 bf;                                           // B[ci][p]: 8 x u16, conflict-free
#pragma unroll
    for (int j = 0; j < 8; ++j) bf[j] = cw[(kb * 32 + h4 * 8 + j) * 18 + l15];
    acc = MFMA(a, bf, acc);
  }
  // ---- softmax over p (= lane&15), hd = 4*h4 + r (h4<2 real, rest dupes) ----
  float at[4];
#pragma unroll
  for (int r = 0; r < 4; ++r) {
    float m = acc[r];
    m = fmaxf(m, __shfl_xor(m, 1, 64));
    m = fmaxf(m, __shfl_xor(m, 2, 64));
    m = fmaxf(m, __shfl_xor(m, 4, 64));
    m = fmaxf(m, __shfl_xor(m, 8, 64));
    float e = __expf(acc[r] - m);
    float s = e;
    s += __shfl_xor(s, 1, 64);
    s += __shfl_xor(s, 2, 64);
    s += __shfl_xor(s, 4, 64);
    s += __shfl_xor(s, 8, 64);
    at[r] = e / s;
  }
  if (h4 < 2) {  // store attn TRANSPOSED: [p][hd]
#pragma unroll
    for (int r = 0; r < 4; ++r) attn_l[w * 512 + l15 * 16 + h4 * 4 + r] = (f16)at[r];
  }
  // ---- P5'': D[m=ci_loc][n=hd] = A(feat)[ci][32p] @ B(attn)[32p][16hd] ----
  // same-wave LDS RAW on attn_l (in-order DS pipe; round-6-proven pattern)
  f16x8 b5;  // B[k=p][n=hd], loop-invariant
#pragma unroll
  for (int j = 0; j < 8; ++j) b5[j] = attn_l[w * 512 + (h4 * 8 + j) * 16 + l15];
  const f32x4 zero = {};
#pragma unroll
  for (int nt = 0; nt < 16; ++nt) {
    // A[m=ci][k=p]: 16B at 4B alignment (stride-18 rows); k>=16 junk x attn-zeros
    const unsigned* ap = (const unsigned*)(cw + (nt * 16 + l15) * 18 + h4 * 8);
    union { unsigned u[4]; f16x8 h; } A;
    A.u[0] = ap[0]; A.u[1] = ap[1]; A.u[2] = ap[2]; A.u[3] = ap[3];
    f32x4 d = MFMA(A.h, b5, zero);
    if (l15 < 8) {  // n = l15 = hd (0..7 real); m = 4*h4 + r -> ci contiguous
      union { f16 h[4]; unsigned long long u; } P;
      P.h[0] = (f16)d[0]; P.h[1] = (f16)d[1]; P.h[2] = (f16)d[2]; P.h[3] = (f16)d[3];
      *(unsigned long long*)(fa + ((size_t)(bz * 8 + l15) * 1024 + pixb + w) * CDIM +
                             nt * 16 + h4 * 4) = P.u;
    }
  }
}

// ---------------- K3: out[c][pix] = (wv @ fa + bv) * gw ----------------
// grid (16 pix-64, 8 hd, nb) x 256. M=64pix, N=32c, K=256ci.
// A (fa) DIRECT from global — no fa_l staging, ONE barrier total.
__global__ __launch_bounds__(256) void k_out(const f16* __restrict__ fa,
                                             const f16* __restrict__ wvh,
                                             const float* __restrict__ bv,
                                             const float* __restrict__ gw,
                                             float* __restrict__ out, int b0) {
  __shared__ __align__(16) f16 wv_l[32 * 264];  // [c][256ci +8pad] 16896 B
  const int t = threadIdx.x;
  const int p16 = blockIdx.x, hd = blockIdx.y, bz = blockIdx.z;
  const int bb = b0 + bz;
  const int lane = t & 63, wid = t >> 6, l15 = lane & 15, h4 = lane >> 4;
#pragma unroll
  for (int it = 0; it < 4; ++it) {
    int e = it * 256 + t, c = e >> 5, ch = e & 31;
    *(f16x8*)(wv_l + c * 264 + ch * 8) =
        *(const f16x8*)(wvh + (size_t)(hd * 32 + c) * CDIM + ch * 8);
  }
  __syncthreads();
  const f16* fap = fa + ((size_t)(bz * 8 + hd) * 1024 + p16 * 64 + wid * 16 + l15) * CDIM +
                   h4 * 8;
  f32x4 acc[2] = {};
#pragma unroll
  for (int kb = 0; kb < 8; ++kb) {
    f16x8 a = *(const f16x8*)(fap + kb * 32);  // A[pix][ci] direct; 64B-contig per h4 group
#pragma unroll
    for (int nt = 0; nt < 2; ++nt) {
      f16x8 b = *(const f16x8*)(wv_l + (nt * 16 + l15) * 264 + kb * 32 + h4 * 8);  // B[ci][c]
      acc[nt] = MFMA(a, b, acc[nt]);
    }
  }
  int pix0 = p16 * 64 + wid * 16 + h4 * 4;
  float4 g = *(const float4*)(gw + bz * 1024 + pix0);
#pragma unroll
  for (int nt = 0; nt < 2; ++nt) {
    int c = hd * 32 + nt * 16 + l15;
    float bvc = bv[c];
    float4 o;
    o.x = (acc[nt][0] + bvc) * g.x;
    o.y = (acc[nt][1] + bvc) * g.y;
    o.z = (acc[nt][2] + bvc) * g.z;
    o.w = (acc[nt][3] + bvc) * g.w;
    *(float4*)(out + (size_t)(bb * CDIM + c) * 1024 + pix0) = o;
  }
}

// ---------------- launcher ----------------
extern "C" void kernel_launch(void* const* d_in, const int* in_sizes, int n_in,
                              void* d_out, int out_size, void* d_ws, size_t ws_size,
                              hipStream_t stream) {
  const float* x = (const float*)d_in[0];
  const float* feat = (const float*)d_in[1];
  const float* wq = (const float*)d_in[2];
  const float* bq = (const float*)d_in[3];
  const float* wk = (const float*)d_in[4];
  // d_in[5] = bk: constant over grid positions -> cancels in softmax, unused
  const float* wv = (const float*)d_in[6];
  const float* bv = (const float*)d_in[7];
  const float* wg = (const float*)d_in[8];
  const float* bg = (const float*)d_in[9];
  float* out = (float*)d_out;

  char* ws = (char*)d_ws;
  f16* W2h = (f16*)ws;                 // 1,048,576 B
  float* b2 = (float*)(ws + 1048576);  //     8,192 B
  f16* wvh = (f16*)(ws + 1056768);     //   131,072 B
  char* dyn = ws + 1187840;

  k_prep_w2<<<dim3(32, 8), 256, 0, stream>>>(wq, bq, wk, wv, W2h, b2, wvh);

  const size_t QK = 4194304, FA = 4194304, GW = 4096;  // per batch
  if (ws_size >= 1187840 + 8 * (QK + FA + GW)) {
    f16* qkp = (f16*)dyn;
    f16* fap = (f16*)(dyn + 8 * QK);
    float* gwp = (float*)(dyn + 8 * (QK + FA));
    k_qkw2<<<dim3(16, 8, 8), 256, 0, stream>>>(x, W2h, b2, wg, bg, qkp, gwp, 0);
    k_attn<<<dim3(32, 8, 8), 256, 0, stream>>>(feat, qkp, fap, 0);
    k_out<<<dim3(16, 8, 8), 256, 0, stream>>>(fap, wvh, bv, gwp, out, 0);
  } else {  // per-batch fallback (~9.6 MB workspace)
    f16* qkp = (f16*)dyn;
    f16* fap = (f16*)(dyn + QK);
    float* gwp = (float*)(dyn + QK + FA);
    for (int b = 0; b < 8; ++b) {
      k_qkw2<<<dim3(16, 8, 1), 256, 0, stream>>>(x, W2h, b2, wg, bg, qkp, gwp, b);
      k_attn<<<dim3(32, 8, 1), 256, 0, stream>>>(feat, qkp, fap, b);
      k_out<<<dim3(16, 8, 1), 256, 0, stream>>>(fap, wvh, bv, gwp, out, b);
    }
  }
}

// Round 10
// 78.790 us; speedup vs baseline: 1.0587x; 1.0587x over previous
//
#include <hip/hip_runtime.h>

#define CDIM 256
#define SCALING 0.17677669529663687f  // 32^-0.5

typedef _Float16 f16;
typedef f16 f16x4 __attribute__((ext_vector_type(4)));
typedef f16 f16x8 __attribute__((ext_vector_type(8)));
typedef float f32x4 __attribute__((ext_vector_type(4)));

// Standard gfx950 16x16x32 f16 fragment mapping (m89-verified D; bench-verified A/B):
//   A[m][k]: lane l, reg j  ->  m = l&15,          k = 8*(l>>4) + j   (k contiguous)
//   B[k][n]: lane l, reg j  ->  k = 8*(l>>4) + j,  n = l&15           (k contiguous)
//   D[m][n]: lane l, reg r  ->  m = 4*(l>>4) + r,  n = l&15
#define MFMA(a, b, c) __builtin_amdgcn_mfma_f32_16x16x32_f16(a, b, c, 0, 0, 0)

__device__ __forceinline__ unsigned pack2(float a, float b) {
  union { f16 h[2]; unsigned u; } r;
  r.h[0] = (f16)a;
  r.h[1] = (f16)b;
  return r.u;
}

// ---------------- K0: W2_hd = scaling * wk_hd^T @ wq_hd ; b2 ; wv -> f16 ----------------
// grid (32 ci-octs, 8 hd) x 256 (t = cx)
__global__ __launch_bounds__(256) void k_prep_w2(const float* __restrict__ wq,
                                                 const float* __restrict__ bq,
                                                 const float* __restrict__ wk,
                                                 const float* __restrict__ wv,
                                                 f16* __restrict__ W2h,
                                                 float* __restrict__ b2,
                                                 f16* __restrict__ wvh) {
  __shared__ float wk_s[32][8];
  const int t = threadIdx.x, ciO = blockIdx.x, hd = blockIdx.y;
  {
    int j = t >> 3, c8 = t & 7;
    wk_s[j][c8] = wk[(hd * 32 + j) * CDIM + ciO * 8 + c8];
    int idx = (hd * 32 + j) * CDIM + ciO * 8 + c8;
    wvh[idx] = (f16)wv[idx];
  }
  float wq_r[32];
#pragma unroll
  for (int j = 0; j < 32; ++j) wq_r[j] = wq[(hd * 32 + j) * CDIM + t];
  __syncthreads();
  for (int c8 = 0; c8 < 8; ++c8) {
    float acc = 0.f;
#pragma unroll
    for (int j = 0; j < 32; ++j) acc = fmaf(wq_r[j], wk_s[j][c8], acc);
    W2h[(size_t)(hd * CDIM + ciO * 8 + c8) * CDIM + t] = (f16)(acc * SCALING);
  }
  if (t < 8) {
    float a = 0.f;
    for (int j = 0; j < 32; ++j) a = fmaf(wk_s[j][t], bq[hd * 32 + j], a);
    b2[hd * CDIM + ciO * 8 + t] = a * SCALING;
  }
}

// ---------------- K1: qk[b][pix][hd][ci] = W2_hd @ x + b2 ; gate ----------------
// grid (16 pix-64-slices, 8 hd, nb) x 256. M=256ci, N=64pix, K=256cx.
// (R8 form — measured-best composite: A via LDS stage, B transposed in LDS.)
__global__ __launch_bounds__(256, 2) void k_qkw2(const float* __restrict__ x,
                                                 const f16* __restrict__ W2h,
                                                 const float* __restrict__ b2,
                                                 const float* __restrict__ wg,
                                                 const float* __restrict__ bg,
                                                 f16* __restrict__ qk,
                                                 float* __restrict__ gw, int b0) {
  __shared__ __align__(16) f16 A_l[256 * 40];  // [ci][32cx + 8 pad]  20480 B
  __shared__ __align__(16) f16 B_l[64 * 40];   // [pix][32cx + 8 pad]  5120 B
  const int t = threadIdx.x;
  const int p16 = blockIdx.x, hd = blockIdx.y, bz = blockIdx.z;
  const int bb = b0 + bz;
  const int lane = t & 63, wid = t >> 6, l15 = lane & 15, h4 = lane >> 4;
  f32x4 acc[4][4] = {};
  float gacc = 0.f;

  for (int kb = 0; kb < 8; ++kb) {
    __syncthreads();
#pragma unroll
    for (int it = 0; it < 4; ++it) {
      int e = it * 256 + t, ci = e >> 2, q = e & 3;
      *(f16x8*)(A_l + ci * 40 + q * 8) =
          *(const f16x8*)(W2h + (size_t)(hd * CDIM + ci) * CDIM + kb * 32 + q * 8);
    }
#pragma unroll
    for (int it = 0; it < 2; ++it) {
      int e = it * 256 + t, cx = e >> 4, p4 = e & 15;
      float4 v = *(const float4*)(x + (size_t)(bb * CDIM + kb * 32 + cx) * 1024 +
                                  p16 * 64 + p4 * 4);
      B_l[(p4 * 4 + 0) * 40 + cx] = (f16)v.x;
      B_l[(p4 * 4 + 1) * 40 + cx] = (f16)v.y;
      B_l[(p4 * 4 + 2) * 40 + cx] = (f16)v.z;
      B_l[(p4 * 4 + 3) * 40 + cx] = (f16)v.w;
    }
    __syncthreads();
    if (hd == 0 && wid == 3) {
#pragma unroll
      for (int cx = 0; cx < 32; ++cx)
        gacc = fmaf(wg[kb * 32 + cx], (float)B_l[lane * 40 + cx], gacc);
    }
    f16x8 a[4], bf[4];
#pragma unroll
    for (int mt = 0; mt < 4; ++mt)
      a[mt] = *(const f16x8*)(A_l + (wid * 64 + mt * 16 + l15) * 40 + h4 * 8);
#pragma unroll
    for (int nt = 0; nt < 4; ++nt)
      bf[nt] = *(const f16x8*)(B_l + (nt * 16 + l15) * 40 + h4 * 8);
#pragma unroll
    for (int mt = 0; mt < 4; ++mt)
#pragma unroll
      for (int nt = 0; nt < 4; ++nt) acc[mt][nt] = MFMA(a[mt], bf[nt], acc[mt][nt]);
  }
#pragma unroll
  for (int mt = 0; mt < 4; ++mt) {
    int ci0 = wid * 64 + mt * 16 + h4 * 4;
    float4 bvv = *(const float4*)(b2 + hd * CDIM + ci0);
#pragma unroll
    for (int nt = 0; nt < 4; ++nt) {
      int pix = p16 * 64 + nt * 16 + l15;
      union { f16 h[4]; unsigned long long u; } P;
      P.h[0] = (f16)(acc[mt][nt][0] + bvv.x);
      P.h[1] = (f16)(acc[mt][nt][1] + bvv.y);
      P.h[2] = (f16)(acc[mt][nt][2] + bvv.z);
      P.h[3] = (f16)(acc[mt][nt][3] + bvv.w);
      *(unsigned long long*)(qk + ((size_t)(bz * 1024 + pix) * 8 + hd) * CDIM + ci0) = P.u;
    }
  }
  if (hd == 0 && wid == 3)
    gw[bz * 1024 + p16 * 64 + lane] = 1.f / (1.f + __expf(-(gacc + bg[0])));
}

// ---------------- K2: fused local attention (single layout, 1 barrier, 4 blk/CU) ------
// block (h, w4, b): 4 query pixels, wave w owns pixel w. LDS = 40960 B exactly.
// cip[px][256ci][18] (16 p + 2 ZEROED pad; stride-18 -> conflict-free P3/P5 reads)
// NEW: qk A-fragments PREFETCHED into regs before staging (HBM latency hidden under
//      feat staging + barrier); staging LDS writes widened b32x2 -> b64.
__global__ __launch_bounds__(256, 4) void k_attn(const float* __restrict__ feat,
                                                 const f16* __restrict__ qk,
                                                 f16* __restrict__ fa, int b0) {
  __shared__ __align__(16) f16 cip[4 * 4608];    // 36864 B [px][ci][18]
  __shared__ __align__(16) f16 attn_l[4 * 512];  //  4096 B [w][32p][16hd]
  const int t = threadIdx.x;
  const int h = blockIdx.x, w4 = blockIdx.y, bz = blockIdx.z;
  const int bb = b0 + bz;
  const int lane = t & 63, w = t >> 6, l15 = lane & 15, h4 = lane >> 4;
  const int pixb = h * 32 + w4 * 4;

  // ---- prefetch P3 A-fragments (global qk; independent of LDS) ----
  const f16* qkg = qk + ((size_t)(bz * 1024 + pixb + w) * 8 + (l15 & 7)) * CDIM;
  f16x8 apre[8];
#pragma unroll
  for (int kb = 0; kb < 8; ++kb) apre[kb] = *(const f16x8*)(qkg + kb * 32 + h4 * 8);

  {  // zero attn_l: p>=16 rows = K-padding zeros; hd>=8 cols = zeros (discarded)
    f16x8 z = {};
    *(f16x8*)(attn_l + t * 8) = z;
  }
  // zero every row's 2-f16 pad (P5 A k=16,17 junk x zero attn rows must be finite)
#pragma unroll
  for (int it = 0; it < 4; ++it) {
    int e = it * 256 + t, px = e >> 8, ci = e & 255;
    *(unsigned*)(cip + px * 4608 + ci * 18 + 16) = 0;
  }
  // stage feat patch: thread -> (px, r, ci) float4; ONE b64 LDS write each
  const float* fb = feat + (size_t)bb * (CDIM * 16384) + (h * 4) * 128 + w4 * 16;
#pragma unroll
  for (int it = 0; it < 16; ++it) {
    int e = it * 256 + t, px = e & 3, r = (e >> 2) & 3, ci = e >> 4;
    float4 v = *(const float4*)(fb + (size_t)ci * 16384 + r * 128 + px * 4);
    uint2 pk;
    pk.x = pack2(v.x, v.y);
    pk.y = pack2(v.z, v.w);
    *(uint2*)(cip + px * 4608 + ci * 18 + r * 4) = pk;  // byte ci*36+r*8: 8B aligned
  }
  __syncthreads();

  // ---- P3: logits[hd][p]; A prefetched (rows 8-15 alias 0-7, dupes discarded) ----
  const f16* cw = cip + w * 4608;
  f32x4 acc = {};
#pragma unroll
  for (int kb = 0; kb < 8; ++kb) {
    f16x8 bf;  // B[ci][p]: 8 x u16, conflict-free (stride-18 bank math)
#pragma unroll
    for (int j = 0; j < 8; ++j) bf[j] = cw[(kb * 32 + h4 * 8 + j) * 18 + l15];
    acc = MFMA(apre[kb], bf, acc);
  }
  // ---- softmax over p (= lane&15), hd = 4*h4 + r (h4<2 real, rest dupes) ----
  float at[4];
#pragma unroll
  for (int r = 0; r < 4; ++r) {
    float m = acc[r];
    m = fmaxf(m, __shfl_xor(m, 1, 64));
    m = fmaxf(m, __shfl_xor(m, 2, 64));
    m = fmaxf(m, __shfl_xor(m, 4, 64));
    m = fmaxf(m, __shfl_xor(m, 8, 64));
    float e = __expf(acc[r] - m);
    float s = e;
    s += __shfl_xor(s, 1, 64);
    s += __shfl_xor(s, 2, 64);
    s += __shfl_xor(s, 4, 64);
    s += __shfl_xor(s, 8, 64);
    at[r] = e / s;
  }
  if (h4 < 2) {  // store attn TRANSPOSED: [p][hd]
#pragma unroll
    for (int r = 0; r < 4; ++r) attn_l[w * 512 + l15 * 16 + h4 * 4 + r] = (f16)at[r];
  }
  // ---- P5'': D[m=ci_loc][n=hd] = A(feat)[ci][32p] @ B(attn)[32p][16hd] ----
  // same-wave LDS RAW on attn_l (in-order DS pipe; round-6-proven pattern)
  f16x8 b5;  // B[k=p][n=hd], loop-invariant
#pragma unroll
  for (int j = 0; j < 8; ++j) b5[j] = attn_l[w * 512 + (h4 * 8 + j) * 16 + l15];
  const f32x4 zero = {};
#pragma unroll
  for (int nt = 0; nt < 16; ++nt) {
    // A[m=ci][k=p]: 16B at 4B alignment (stride-18 rows); k>=16 junk x attn-zeros
    const unsigned* ap = (const unsigned*)(cw + (nt * 16 + l15) * 18 + h4 * 8);
    union { unsigned u[4]; f16x8 h; } A;
    A.u[0] = ap[0]; A.u[1] = ap[1]; A.u[2] = ap[2]; A.u[3] = ap[3];
    f32x4 d = MFMA(A.h, b5, zero);
    if (l15 < 8) {  // n = l15 = hd (0..7 real); m = 4*h4 + r -> ci contiguous
      union { f16 h[4]; unsigned long long u; } P;
      P.h[0] = (f16)d[0]; P.h[1] = (f16)d[1]; P.h[2] = (f16)d[2]; P.h[3] = (f16)d[3];
      *(unsigned long long*)(fa + ((size_t)(bz * 8 + l15) * 1024 + pixb + w) * CDIM +
                             nt * 16 + h4 * 4) = P.u;
    }
  }
}

// ---------------- K3: out[c][pix] = (wv @ fa + bv) * gw ----------------
// grid (16 pix-64, 8 hd, nb) x 256. M=64pix, N=32c, K=256ci.
// A (fa) direct from global, PREFETCHED before the wv_l barrier (latency hidden).
__global__ __launch_bounds__(256) void k_out(const f16* __restrict__ fa,
                                             const f16* __restrict__ wvh,
                                             const float* __restrict__ bv,
                                             const float* __restrict__ gw,
                                             float* __restrict__ out, int b0) {
  __shared__ __align__(16) f16 wv_l[32 * 264];  // [c][256ci +8pad] 16896 B
  const int t = threadIdx.x;
  const int p16 = blockIdx.x, hd = blockIdx.y, bz = blockIdx.z;
  const int bb = b0 + bz;
  const int lane = t & 63, wid = t >> 6, l15 = lane & 15, h4 = lane >> 4;

  // prefetch all 8 A-fragments first (independent of wv staging)
  const f16* fap = fa + ((size_t)(bz * 8 + hd) * 1024 + p16 * 64 + wid * 16 + l15) * CDIM +
                   h4 * 8;
  f16x8 apre[8];
#pragma unroll
  for (int kb = 0; kb < 8; ++kb) apre[kb] = *(const f16x8*)(fap + kb * 32);

#pragma unroll
  for (int it = 0; it < 4; ++it) {
    int e = it * 256 + t, c = e >> 5, ch = e & 31;
    *(f16x8*)(wv_l + c * 264 + ch * 8) =
        *(const f16x8*)(wvh + (size_t)(hd * 32 + c) * CDIM + ch * 8);
  }
  __syncthreads();
  f32x4 acc[2] = {};
#pragma unroll
  for (int kb = 0; kb < 8; ++kb) {
#pragma unroll
    for (int nt = 0; nt < 2; ++nt) {
      f16x8 b = *(const f16x8*)(wv_l + (nt * 16 + l15) * 264 + kb * 32 + h4 * 8);  // B[ci][c]
      acc[nt] = MFMA(apre[kb], b, acc[nt]);
    }
  }
  int pix0 = p16 * 64 + wid * 16 + h4 * 4;
  float4 g = *(const float4*)(gw + bz * 1024 + pix0);
#pragma unroll
  for (int nt = 0; nt < 2; ++nt) {
    int c = hd * 32 + nt * 16 + l15;
    float bvc = bv[c];
    float4 o;
    o.x = (acc[nt][0] + bvc) * g.x;
    o.y = (acc[nt][1] + bvc) * g.y;
    o.z = (acc[nt][2] + bvc) * g.z;
    o.w = (acc[nt][3] + bvc) * g.w;
    *(float4*)(out + (size_t)(bb * CDIM + c) * 1024 + pix0) = o;
  }
}

// ---------------- launcher ----------------
extern "C" void kernel_launch(void* const* d_in, const int* in_sizes, int n_in,
                              void* d_out, int out_size, void* d_ws, size_t ws_size,
                              hipStream_t stream) {
  const float* x = (const float*)d_in[0];
  const float* feat = (const float*)d_in[1];
  const float* wq = (const float*)d_in[2];
  const float* bq = (const float*)d_in[3];
  const float* wk = (const float*)d_in[4];
  // d_in[5] = bk: constant over grid positions -> cancels in softmax, unused
  const float* wv = (const float*)d_in[6];
  const float* bv = (const float*)d_in[7];
  const float* wg = (const float*)d_in[8];
  const float* bg = (const float*)d_in[9];
  float* out = (float*)d_out;

  char* ws = (char*)d_ws;
  f16* W2h = (f16*)ws;                 // 1,048,576 B
  float* b2 = (float*)(ws + 1048576);  //     8,192 B
  f16* wvh = (f16*)(ws + 1056768);     //   131,072 B
  char* dyn = ws + 1187840;

  k_prep_w2<<<dim3(32, 8), 256, 0, stream>>>(wq, bq, wk, wv, W2h, b2, wvh);

  const size_t QK = 4194304, FA = 4194304, GW = 4096;  // per batch
  if (ws_size >= 1187840 + 8 * (QK + FA + GW)) {
    f16* qkp = (f16*)dyn;
    f16* fap = (f16*)(dyn + 8 * QK);
    float* gwp = (float*)(dyn + 8 * (QK + FA));
    k_qkw2<<<dim3(16, 8, 8), 256, 0, stream>>>(x, W2h, b2, wg, bg, qkp, gwp, 0);
    k_attn<<<dim3(32, 8, 8), 256, 0, stream>>>(feat, qkp, fap, 0);
    k_out<<<dim3(16, 8, 8), 256, 0, stream>>>(fap, wvh, bv, gwp, out, 0);
  } else {  // per-batch fallback (~9.6 MB workspace)
    f16* qkp = (f16*)dyn;
    f16* fap = (f16*)(dyn + QK);
    float* gwp = (float*)(dyn + QK + FA);
    for (int b = 0; b < 8; ++b) {
      k_qkw2<<<dim3(16, 8, 1), 256, 0, stream>>>(x, W2h, b2, wg, bg, qkp, gwp, b);
      k_attn<<<dim3(32, 8, 1), 256, 0, stream>>>(feat, qkp, fap, b);
      k_out<<<dim3(16, 8, 1), 256, 0, stream>>>(fap, wvh, bv, gwp, out, b);
    }
  }
}